// Round 5
// baseline (713.488 us; speedup 1.0000x reference)
//
#include <hip/hip_runtime.h>

// ---------------------------------------------------------------------------
// WindowAttention: x[2048,49,512] fp32 -> out[2048,49,512] fp32
// R1: T2 LDS XOR-swizzle + T1 XCD swizzle (bank conflicts -> 0).   [593us]
// R2: 8-phase 256^2 port REGRESSED (K=512 too shallow) - reverted.
// R3: fused x-cvt into GEMM1 + raw s_barrier guard -> RACE (absmax 3.4e-2).
// R4: keep fusion; restore full __syncthreads() guards (R1-proven sync
//     structure); A-prefetch issued after mid-barrier (overlaps compute).
// ---------------------------------------------------------------------------

typedef unsigned short ushort_t;
typedef __bf16 bf16x8 __attribute__((ext_vector_type(8)));
typedef float f32x4 __attribute__((ext_vector_type(4)));
typedef unsigned short us8 __attribute__((ext_vector_type(8)));

#define SCALE_F 0.17677669529663687f   // 32^-0.5
constexpr size_t QKV_REG = 2048ULL * 16 * 49 * 32;   // elems per q/k/v region

// RNE float -> bf16 (as raw ushort)
__device__ __forceinline__ ushort_t f2bf(float f) {
  unsigned u = __builtin_bit_cast(unsigned, f);
  u += 0x7FFFu + ((u >> 16) & 1u);
  return (ushort_t)(u >> 16);
}

__device__ __forceinline__ uint4 pack8(float4 a, float4 b) {
  uint4 r;
  r.x = (unsigned)f2bf(a.x) | ((unsigned)f2bf(a.y) << 16);
  r.y = (unsigned)f2bf(a.z) | ((unsigned)f2bf(a.w) << 16);
  r.z = (unsigned)f2bf(b.x) | ((unsigned)f2bf(b.y) << 16);
  r.w = (unsigned)f2bf(b.z) | ((unsigned)f2bf(b.w) << 16);
  return r;
}

// async global->LDS, 16B per lane; lds base must be wave-uniform
__device__ __forceinline__ void gload_lds16(const void* g, void* l) {
  __builtin_amdgcn_global_load_lds(
      (const __attribute__((address_space(1))) void*)g,
      (__attribute__((address_space(3))) void*)l, 16, 0, 0);
}

// ---------------------------------------------------------------------------
// fp32 -> bf16 conversion (weights only), 4 elems/thread
// ---------------------------------------------------------------------------
__global__ __launch_bounds__(256) void k_cvt(const float* __restrict__ in,
                                             ushort_t* __restrict__ out, int n4) {
  int i = blockIdx.x * blockDim.x + threadIdx.x;
  if (i >= n4) return;
  float4 v = reinterpret_cast<const float4*>(in)[i];
  ushort4 o = make_ushort4(f2bf(v.x), f2bf(v.y), f2bf(v.z), f2bf(v.w));
  reinterpret_cast<ushort4*>(out)[i] = o;
}

// ---------------------------------------------------------------------------
// GEMM1 fused: qkv[m][o] = sum_k bf16(X[m][k]) * W[o][k] + bias[o], K=512.
// X fp32 row-major; W bf16 row-major. Tile 128x128, BK=64, 4 waves.
// A staged via registers (f32 load -> bf16 pack -> XOR-swizzled ds_write,
// prefetched one K-step ahead during compute); W staged via global_load_lds
// with pre-swizzled source. LDS slot (row,c) holds logical chunk c ^ (row&7).
// Sync: full __syncthreads() on BOTH barriers (R1-proven; raw s_barrier raced).
// Epilogue scatters to qkv layout [3][B,H,N,d] bf16.
// ---------------------------------------------------------------------------
__global__ __launch_bounds__(256) void k_gemm1f(const float* __restrict__ X,
                                                const ushort_t* __restrict__ W,
                                                const float* __restrict__ bias,
                                                ushort_t* __restrict__ out_qkv) {
  __shared__ __align__(16) ushort_t As[128][64];
  __shared__ __align__(16) ushort_t Ws[128][64];
  constexpr int nt_o = 12;

  const int tid  = threadIdx.x;
  const int lane = tid & 63;
  const int wv   = tid >> 6;
  const int wr   = wv >> 1, wc = wv & 1;

  const int cpx = gridDim.x >> 3;
  const int lid = (blockIdx.x & 7) * cpx + (blockIdx.x >> 3);
  const int bm  = lid / nt_o;
  const int bo  = lid - bm * nt_o;
  const size_t m0 = (size_t)bm * 128;
  const int o0    = bo * 128;

  f32x4 acc[4][4];
#pragma unroll
  for (int i = 0; i < 4; i++)
#pragma unroll
    for (int j = 0; j < 4; j++) acc[i][j] = f32x4{0.f, 0.f, 0.f, 0.f};

  // A staging (reg path): lane covers rows wv*32 + (lane>>3) + 8i, natural
  // source cols (lane&7)*8; ds_write slot chunk = (lane&7) ^ (lane>>3).
  const int arow0 = wv * 32 + (lane >> 3);
  const int acol  = (lane & 7) * 8;
  const int aswc  = ((lane & 7) ^ (lane >> 3)) * 8;
  const float* Xg = X + (m0 + arow0) * 512 + acol;

  // W staging (gload_lds path, pre-swizzled source)
  const ushort_t* Wg = W + (size_t)(o0 + arow0) * 512 + (size_t)aswc;

  auto loadA = [&](int kt, float4 (&ar)[4][2]) {
#pragma unroll
    for (int i = 0; i < 4; i++) {
      const float* g = Xg + (size_t)i * (8 * 512) + kt * 64;
      ar[i][0] = *reinterpret_cast<const float4*>(g);
      ar[i][1] = *reinterpret_cast<const float4*>(g + 4);
    }
  };
  auto writeA = [&](const float4 (&ar)[4][2]) {
#pragma unroll
    for (int i = 0; i < 4; i++) {
      uint4 p = pack8(ar[i][0], ar[i][1]);
      *reinterpret_cast<uint4*>(&As[arow0 + i * 8][aswc]) = p;
    }
  };

  float4 areg[2][4][2];
  loadA(0, areg[0]);

#pragma unroll
  for (int kt = 0; kt < 8; ++kt) {
    // stage W(kt) via gload_lds
#pragma unroll
    for (int i = 0; i < 4; i++)
      gload_lds16(Wg + (size_t)i * (8 * 512) + kt * 64, &Ws[wv * 32 + i * 8][0]);
    // stage A(kt) from regs (vmcnt wait on the prefetch inserted by compiler)
    writeA(areg[kt & 1]);
    __syncthreads();

    // prefetch A(kt+1) during compute; drained by the guard __syncthreads
    if (kt < 7) loadA(kt + 1, areg[(kt + 1) & 1]);

    const int fr = lane & 15;
#pragma unroll
    for (int kk = 0; kk < 2; ++kk) {
      const int ch = kk * 4 + (lane >> 4);
      const int cb = ((ch ^ (lane & 7)) << 3);
      uint4 ar[4], br[4];
#pragma unroll
      for (int mi = 0; mi < 4; mi++)
        ar[mi] = *reinterpret_cast<const uint4*>(&As[wr * 64 + mi * 16 + fr][cb]);
#pragma unroll
      for (int ni = 0; ni < 4; ni++)
        br[ni] = *reinterpret_cast<const uint4*>(&Ws[wc * 64 + ni * 16 + fr][cb]);
#pragma unroll
      for (int mi = 0; mi < 4; mi++)
#pragma unroll
        for (int ni = 0; ni < 4; ni++)
          acc[mi][ni] = __builtin_amdgcn_mfma_f32_16x16x32_bf16(
              __builtin_bit_cast(bf16x8, ar[mi]),
              __builtin_bit_cast(bf16x8, br[ni]), acc[mi][ni], 0, 0, 0);
    }
    __syncthreads();   // guard: full drain (raw s_barrier here raced in R3)
  }

  const int colbase = lane & 15;
  const int rowgrp  = (lane >> 4) * 4;
#pragma unroll
  for (int mi = 0; mi < 4; mi++) {
#pragma unroll
    for (int r = 0; r < 4; r++) {
      const int t = (int)m0 + wr * 64 + mi * 16 + rowgrp + r;  // token
      const int b = t / 49;
      const int n = t - b * 49;
#pragma unroll
      for (int ni = 0; ni < 4; ni++) {
        const int o = o0 + wc * 64 + ni * 16 + colbase;
        const int which = o >> 9;
        const int h = (o >> 5) & 15;
        const int dd = o & 31;
        const size_t dst = (size_t)which * QKV_REG +
                           (((size_t)b * 16 + h) * 49 + n) * 32 + dd;
        out_qkv[dst] = f2bf(acc[mi][ni][r] + bias[o]);
      }
    }
  }
}

// ---------------------------------------------------------------------------
// GEMM2: out[m][o] = sum_k A[m][k]*W[o][k] + bias[o]  (bf16 in, fp32 out)
// R1-proven structure: 128x128 tile, BK=64, gload_lds both operands,
// XOR swizzle, full __syncthreads() both barriers.
// ---------------------------------------------------------------------------
__global__ __launch_bounds__(256) void k_gemmB(const ushort_t* __restrict__ A,
                                               const ushort_t* __restrict__ W,
                                               const float* __restrict__ bias,
                                               float* __restrict__ out_f,
                                               int nt_o) {
  __shared__ __align__(16) ushort_t As[128][64];
  __shared__ __align__(16) ushort_t Ws[128][64];

  const int tid  = threadIdx.x;
  const int lane = tid & 63;
  const int wv   = tid >> 6;
  const int wr   = wv >> 1, wc = wv & 1;

  const int cpx = gridDim.x >> 3;
  const int lid = (blockIdx.x & 7) * cpx + (blockIdx.x >> 3);
  const int bm  = lid / nt_o;
  const int bo  = lid - bm * nt_o;
  const size_t m0 = (size_t)bm * 128;
  const int o0    = bo * 128;

  f32x4 acc[4][4];
#pragma unroll
  for (int i = 0; i < 4; i++)
#pragma unroll
    for (int j = 0; j < 4; j++) acc[i][j] = f32x4{0.f, 0.f, 0.f, 0.f};

  const int srow   = wv * 32 + (lane >> 3);
  const int schunk = (((lane & 7) ^ (lane >> 3)) * 8);

  for (int kt = 0; kt < 8; ++kt) {
    const int k0 = kt * 64;
#pragma unroll
    for (int i = 0; i < 4; i++)
      gload_lds16(A + (m0 + srow + i * 8) * 512 + k0 + schunk,
                  &As[wv * 32 + i * 8][0]);
#pragma unroll
    for (int i = 0; i < 4; i++)
      gload_lds16(W + (size_t)(o0 + srow + i * 8) * 512 + k0 + schunk,
                  &Ws[wv * 32 + i * 8][0]);
    __syncthreads();
    const int fr = lane & 15;
#pragma unroll
    for (int kk = 0; kk < 2; ++kk) {
      const int ch = kk * 4 + (lane >> 4);
      const int cb = ((ch ^ (lane & 7)) << 3);
      uint4 ar[4], br[4];
#pragma unroll
      for (int mi = 0; mi < 4; mi++)
        ar[mi] = *reinterpret_cast<const uint4*>(&As[wr * 64 + mi * 16 + fr][cb]);
#pragma unroll
      for (int ni = 0; ni < 4; ni++)
        br[ni] = *reinterpret_cast<const uint4*>(&Ws[wc * 64 + ni * 16 + fr][cb]);
#pragma unroll
      for (int mi = 0; mi < 4; mi++)
#pragma unroll
        for (int ni = 0; ni < 4; ni++)
          acc[mi][ni] = __builtin_amdgcn_mfma_f32_16x16x32_bf16(
              __builtin_bit_cast(bf16x8, ar[mi]),
              __builtin_bit_cast(bf16x8, br[ni]), acc[mi][ni], 0, 0, 0);
    }
    __syncthreads();
  }

  const int colbase = lane & 15;
  const int rowgrp  = (lane >> 4) * 4;
#pragma unroll
  for (int ni = 0; ni < 4; ni++) {
    const int o = o0 + wc * 64 + ni * 16 + colbase;
    const float bv = bias[o];
#pragma unroll
    for (int mi = 0; mi < 4; mi++) {
      const size_t mrow = m0 + wr * 64 + mi * 16 + rowgrp;
#pragma unroll
      for (int r = 0; r < 4; r++)
        out_f[(mrow + r) * 512 + o] = acc[mi][ni][r] + bv;
    }
  }
}

// ---------------------------------------------------------------------------
// Attention: one block per (b,h). 4 waves, wave mt owns query rows
// [16*mt, 16*mt+16). S = scale*Q K^T + mask ; softmax ; O = P V / rowsum.
// Vt and Ps use the chunk-XOR-swizzled LDS layout. (unchanged from R1)
// ---------------------------------------------------------------------------
__global__ __launch_bounds__(256) void k_attn(const ushort_t* __restrict__ qkv,
                                              const float* __restrict__ mask,
                                              ushort_t* __restrict__ aout) {
  __shared__ __align__(16) ushort_t Vt[32][64];
  __shared__ __align__(16) ushort_t Ps[4][16][64];

  const int tid  = threadIdx.x;
  const int lane = tid & 63;
  const int mt   = tid >> 6;
  const int bh   = blockIdx.x;
  const int b    = bh >> 4, h = bh & 15;
  const int w    = b & 63;
  const size_t base = (size_t)bh * (49 * 32);
  const ushort_t* qb = qkv + base;
  const ushort_t* kb = qkv + QKV_REG + base;
  const ushort_t* vb = qkv + 2 * QKV_REG + base;

  reinterpret_cast<uint4*>(&Vt[0][0])[tid] = make_uint4(0, 0, 0, 0);
  __syncthreads();
  if (tid < 196) {
    const int n = tid >> 2, d0 = (tid & 3) * 8;
    uint4 raw = *reinterpret_cast<const uint4*>(vb + n * 32 + d0);
    us8 e = __builtin_bit_cast(us8, raw);
#pragma unroll
    for (int j = 0; j < 8; j++)
      Vt[d0 + j][(((n >> 3) ^ j) << 3) | (n & 7)] = e[j];
  }
  __syncthreads();

  const int arow = lane & 15;
  const int kc   = (lane >> 4) * 8;

  uint4 qraw = *reinterpret_cast<const uint4*>(qb + (mt * 16 + arow) * 32 + kc);
  bf16x8 qa = __builtin_bit_cast(bf16x8, qraw);
  f32x4 s[4];
#pragma unroll
  for (int ni = 0; ni < 4; ni++) {
    uint4 kraw = *reinterpret_cast<const uint4*>(kb + (ni * 16 + arow) * 32 + kc);
    f32x4 z = {0.f, 0.f, 0.f, 0.f};
    s[ni] = __builtin_amdgcn_mfma_f32_16x16x32_bf16(
        qa, __builtin_bit_cast(bf16x8, kraw), z, 0, 0, 0);
  }

  const int rg = (lane >> 4) * 4;
  float rsum[4];
#pragma unroll
  for (int r = 0; r < 4; r++) {
    const int qr = mt * 16 + rg + r;
    float sv[4];
    float mx = -1e30f;
#pragma unroll
    for (int ni = 0; ni < 4; ni++) {
      const int col = ni * 16 + arow;
      float v;
      if (qr < 49 && col < 49)
        v = s[ni][r] * SCALE_F + mask[(size_t)w * 2401 + qr * 49 + col];
      else
        v = -1e30f;
      sv[ni] = v;
      mx = fmaxf(mx, v);
    }
#pragma unroll
    for (int off = 1; off < 16; off <<= 1) mx = fmaxf(mx, __shfl_xor(mx, off));
    float sum = 0.f;
    const int prow = rg + r;
#pragma unroll
    for (int ni = 0; ni < 4; ni++) {
      float p = __expf(sv[ni] - mx);
      sum += p;
      const int pcol = ni * 16 + arow;
      Ps[mt][prow][(((pcol >> 3) ^ (prow & 7)) << 3) | (pcol & 7)] = f2bf(p);
    }
#pragma unroll
    for (int off = 1; off < 16; off <<= 1) sum += __shfl_xor(sum, off);
    rsum[r] = sum;
  }

  __syncthreads();

  f32x4 o0 = {0.f, 0.f, 0.f, 0.f}, o1 = {0.f, 0.f, 0.f, 0.f};
#pragma unroll
  for (int kk = 0; kk < 2; kk++) {
    const int ch = kk * 4 + (lane >> 4);
    const int cb = ((ch ^ (lane & 7)) << 3);
    uint4 praw = *reinterpret_cast<const uint4*>(&Ps[mt][arow][cb]);
    bf16x8 pa = __builtin_bit_cast(bf16x8, praw);
    uint4 v0 = *reinterpret_cast<const uint4*>(&Vt[arow][cb]);
    uint4 v1 = *reinterpret_cast<const uint4*>(&Vt[16 + arow][cb]);
    o0 = __builtin_amdgcn_mfma_f32_16x16x32_bf16(pa, __builtin_bit_cast(bf16x8, v0), o0, 0, 0, 0);
    o1 = __builtin_amdgcn_mfma_f32_16x16x32_bf16(pa, __builtin_bit_cast(bf16x8, v1), o1, 0, 0, 0);
  }

#pragma unroll
  for (int r = 0; r < 4; r++) {
    const int qr = mt * 16 + rg + r;
    if (qr < 49) {
      const float inv = 1.f / rsum[r];
      aout[((size_t)b * 49 + qr) * 512 + h * 32 + arow]      = f2bf(o0[r] * inv);
      aout[((size_t)b * 49 + qr) * 512 + h * 32 + 16 + arow] = f2bf(o1[r] * inv);
    }
  }
}

// ---------------------------------------------------------------------------
// launch
// ---------------------------------------------------------------------------
extern "C" void kernel_launch(void* const* d_in, const int* in_sizes, int n_in,
                              void* d_out, int out_size, void* d_ws, size_t ws_size,
                              hipStream_t stream) {
  const float* x      = (const float*)d_in[0];
  const float* mask   = (const float*)d_in[1];
  const float* W_qkv  = (const float*)d_in[2];
  const float* b_qkv  = (const float*)d_in[3];
  const float* W_proj = (const float*)d_in[4];
  const float* b_proj = (const float*)d_in[5];
  float* out = (float*)d_out;

  // ws layout (bf16 elems): qkv(q,k,v) | attn_out | Wqkv_b | Wproj_b
  ushort_t* ws     = (ushort_t*)d_ws;
  ushort_t* qkvb   = ws;                                  // 3*51,380,224
  ushort_t* aoutb  = ws + 154140672UL;                    // 51,380,224
  ushort_t* wqkvb  = ws + 205520896UL;                    // 786,432
  ushort_t* wprojb = ws + 206307328UL;                    // 262,144

  const int n4q = 786432 / 4, n4p = 262144 / 4;
  k_cvt<<<(n4q + 255) / 256, 256, 0, stream>>>(W_qkv, wqkvb, n4q);
  k_cvt<<<(n4p + 255) / 256, 256, 0, stream>>>(W_proj, wprojb, n4p);

  // GEMM1 (fused x-cvt): [100352,512]f32 x [1536,512]^T -> qkv scatter.
  k_gemm1f<<<784 * 12, 256, 0, stream>>>(x, wqkvb, b_qkv, qkvb);

  // attention: one block per (b,h)
  k_attn<<<2048 * 16, 256, 0, stream>>>(qkvb, mask, aoutb);

  // GEMM2: [100352,512] x [512,512]^T + bias -> fp32 out.
  k_gemmB<<<784 * 4, 256, 0, stream>>>(aoutb, wprojb, b_proj, out, 4);
}

// Round 6
// 601.694 us; speedup vs baseline: 1.1858x; 1.1858x over previous
//
#include <hip/hip_runtime.h>

// ---------------------------------------------------------------------------
// WindowAttention: x[2048,49,512] fp32 -> out[2048,49,512] fp32
// R1: T2 LDS XOR-swizzle + T1 XCD swizzle (bank conflicts -> 0).   [593us]
// R2: 8-phase 256^2 port REGRESSED (K=512 too shallow) - reverted.
// R3: fused x-cvt + raw s_barrier guard -> RACE (raw barrier is no fence).
// R4: fused x-cvt + full syncthreads -> 480us GEMM1 (reg-staged A spills;
//     guard drains prefetch). Fusion abandoned.
// R5: R1 structure + 2-deep double-buffered K-pipeline with counted
//     vmcnt(8) (T4-minimum); raw s_barrier bracketed by sched_barrier(0)
//     (m201-verified fencing). cvt-x separate again.
// ---------------------------------------------------------------------------

typedef unsigned short ushort_t;
typedef __bf16 bf16x8 __attribute__((ext_vector_type(8)));
typedef float f32x4 __attribute__((ext_vector_type(4)));
typedef unsigned short us8 __attribute__((ext_vector_type(8)));

#define SCALE_F 0.17677669529663687f   // 32^-0.5
constexpr size_t QKV_REG = 2048ULL * 16 * 49 * 32;   // elems per q/k/v region

// RNE float -> bf16 (as raw ushort)
__device__ __forceinline__ ushort_t f2bf(float f) {
  unsigned u = __builtin_bit_cast(unsigned, f);
  u += 0x7FFFu + ((u >> 16) & 1u);
  return (ushort_t)(u >> 16);
}

// async global->LDS, 16B per lane; lds base must be wave-uniform
__device__ __forceinline__ void gload_lds16(const void* g, void* l) {
  __builtin_amdgcn_global_load_lds(
      (const __attribute__((address_space(1))) void*)g,
      (__attribute__((address_space(3))) void*)l, 16, 0, 0);
}

// ---------------------------------------------------------------------------
// fp32 -> bf16 conversion, 4 elems/thread
// ---------------------------------------------------------------------------
__global__ __launch_bounds__(256) void k_cvt(const float* __restrict__ in,
                                             ushort_t* __restrict__ out, int n4) {
  int i = blockIdx.x * blockDim.x + threadIdx.x;
  if (i >= n4) return;
  float4 v = reinterpret_cast<const float4*>(in)[i];
  ushort4 o = make_ushort4(f2bf(v.x), f2bf(v.y), f2bf(v.z), f2bf(v.w));
  reinterpret_cast<ushort4*>(out)[i] = o;
}

// ---------------------------------------------------------------------------
// Pipelined GEMM: C[m][o] = sum_k A[m][k]*W[o][k] + bias[o], K=512, bf16 in.
// Tile 128x128, BK=64, 4 waves, XOR-swizzled LDS (slot(row,c) = chunk
// c^(row&7), staged via pre-swizzled global source).
// 2-deep double buffer: stage(kt+2)->buf[kt&1] after the guard barrier;
// top-of-loop waits vmcnt(8) only (stage kt retired, kt+1 in flight).
// Raw s_barrier fenced with sched_barrier(0) on both sides of each phase.
// EPI=0: scatter to qkv layout [3][B,H,N,d] bf16.  EPI=1: fp32 out.
// ---------------------------------------------------------------------------
template <int EPI>
__global__ __launch_bounds__(256) void k_gemmP(const ushort_t* __restrict__ A,
                                               const ushort_t* __restrict__ W,
                                               const float* __restrict__ bias,
                                               ushort_t* __restrict__ out_qkv,
                                               float* __restrict__ out_f,
                                               int nt_o) {
  __shared__ __align__(16) ushort_t As[2][128][64];
  __shared__ __align__(16) ushort_t Ws[2][128][64];

  const int tid  = threadIdx.x;
  const int lane = tid & 63;
  const int wv   = tid >> 6;
  const int wr   = wv >> 1, wc = wv & 1;

  const int cpx = gridDim.x >> 3;
  const int lid = (blockIdx.x & 7) * cpx + (blockIdx.x >> 3);
  const int bm  = lid / nt_o;
  const int bo  = lid - bm * nt_o;
  const size_t m0 = (size_t)bm * 128;
  const int o0    = bo * 128;

  f32x4 acc[4][4];
#pragma unroll
  for (int i = 0; i < 4; i++)
#pragma unroll
    for (int j = 0; j < 4; j++) acc[i][j] = f32x4{0.f, 0.f, 0.f, 0.f};

  const int srow   = wv * 32 + (lane >> 3);
  const int schunk = (((lane & 7) ^ (lane >> 3)) * 8);
  const ushort_t* Ags = A + (m0 + srow) * 512 + schunk;
  const ushort_t* Wgs = W + (size_t)(o0 + srow) * 512 + schunk;

  // 8 gload_lds16 per stage call (4 A + 4 W) per thread
  auto stage = [&](int kt, int bb) {
#pragma unroll
    for (int i = 0; i < 4; i++)
      gload_lds16(Ags + (size_t)i * (8 * 512) + kt * 64, &As[bb][wv * 32 + i * 8][0]);
#pragma unroll
    for (int i = 0; i < 4; i++)
      gload_lds16(Wgs + (size_t)i * (8 * 512) + kt * 64, &Ws[bb][wv * 32 + i * 8][0]);
  };

  const int fr = lane & 15;
  auto compute = [&](int bb) {
#pragma unroll
    for (int kk = 0; kk < 2; ++kk) {
      const int ch = kk * 4 + (lane >> 4);
      const int cb = ((ch ^ (lane & 7)) << 3);
      uint4 ar[4], br[4];
#pragma unroll
      for (int mi = 0; mi < 4; mi++)
        ar[mi] = *reinterpret_cast<const uint4*>(&As[bb][wr * 64 + mi * 16 + fr][cb]);
#pragma unroll
      for (int ni = 0; ni < 4; ni++)
        br[ni] = *reinterpret_cast<const uint4*>(&Ws[bb][wc * 64 + ni * 16 + fr][cb]);
#pragma unroll
      for (int mi = 0; mi < 4; mi++)
#pragma unroll
        for (int ni = 0; ni < 4; ni++)
          acc[mi][ni] = __builtin_amdgcn_mfma_f32_16x16x32_bf16(
              __builtin_bit_cast(bf16x8, ar[mi]),
              __builtin_bit_cast(bf16x8, br[ni]), acc[mi][ni], 0, 0, 0);
    }
  };

  // prologue: two K-tiles in flight
  stage(0, 0);
  stage(1, 1);

  for (int kt = 0; kt < 7; ++kt) {
    asm volatile("s_waitcnt vmcnt(8)" ::: "memory");   // stage(kt) retired
    __builtin_amdgcn_s_barrier();
    __builtin_amdgcn_sched_barrier(0);
    compute(kt & 1);
    __builtin_amdgcn_sched_barrier(0);
    __builtin_amdgcn_s_barrier();                      // all waves done reading buf
    if (kt < 6) stage(kt + 2, kt & 1);
  }
  asm volatile("s_waitcnt vmcnt(0)" ::: "memory");     // stage(7) retired
  __builtin_amdgcn_s_barrier();
  __builtin_amdgcn_sched_barrier(0);
  compute(1);

  // ---- epilogue ----
  const int colbase = lane & 15;
  const int rowgrp  = (lane >> 4) * 4;

  if constexpr (EPI == 1) {
#pragma unroll
    for (int ni = 0; ni < 4; ni++) {
      const int o = o0 + wc * 64 + ni * 16 + colbase;
      const float bv = bias[o];
#pragma unroll
      for (int mi = 0; mi < 4; mi++) {
        const size_t mrow = m0 + wr * 64 + mi * 16 + rowgrp;
#pragma unroll
        for (int r = 0; r < 4; r++)
          out_f[(mrow + r) * 512 + o] = acc[mi][ni][r] + bv;
      }
    }
  } else {
#pragma unroll
    for (int mi = 0; mi < 4; mi++) {
#pragma unroll
      for (int r = 0; r < 4; r++) {
        const int t = (int)m0 + wr * 64 + mi * 16 + rowgrp + r;  // token
        const int b = t / 49;
        const int n = t - b * 49;
#pragma unroll
        for (int ni = 0; ni < 4; ni++) {
          const int o = o0 + wc * 64 + ni * 16 + colbase;
          const int which = o >> 9;
          const int h = (o >> 5) & 15;
          const int dd = o & 31;
          const size_t dst = (size_t)which * QKV_REG +
                             (((size_t)b * 16 + h) * 49 + n) * 32 + dd;
          out_qkv[dst] = f2bf(acc[mi][ni][r] + bias[o]);
        }
      }
    }
  }
}

// ---------------------------------------------------------------------------
// Attention: one block per (b,h). 4 waves, wave mt owns query rows
// [16*mt, 16*mt+16). S = scale*Q K^T + mask ; softmax ; O = P V / rowsum.
// Vt and Ps use the chunk-XOR-swizzled LDS layout. (unchanged from R1)
// ---------------------------------------------------------------------------
__global__ __launch_bounds__(256) void k_attn(const ushort_t* __restrict__ qkv,
                                              const float* __restrict__ mask,
                                              ushort_t* __restrict__ aout) {
  __shared__ __align__(16) ushort_t Vt[32][64];
  __shared__ __align__(16) ushort_t Ps[4][16][64];

  const int tid  = threadIdx.x;
  const int lane = tid & 63;
  const int mt   = tid >> 6;
  const int bh   = blockIdx.x;
  const int b    = bh >> 4, h = bh & 15;
  const int w    = b & 63;
  const size_t base = (size_t)bh * (49 * 32);
  const ushort_t* qb = qkv + base;
  const ushort_t* kb = qkv + QKV_REG + base;
  const ushort_t* vb = qkv + 2 * QKV_REG + base;

  reinterpret_cast<uint4*>(&Vt[0][0])[tid] = make_uint4(0, 0, 0, 0);
  __syncthreads();
  if (tid < 196) {
    const int n = tid >> 2, d0 = (tid & 3) * 8;
    uint4 raw = *reinterpret_cast<const uint4*>(vb + n * 32 + d0);
    us8 e = __builtin_bit_cast(us8, raw);
#pragma unroll
    for (int j = 0; j < 8; j++)
      Vt[d0 + j][(((n >> 3) ^ j) << 3) | (n & 7)] = e[j];
  }
  __syncthreads();

  const int arow = lane & 15;
  const int kc   = (lane >> 4) * 8;

  uint4 qraw = *reinterpret_cast<const uint4*>(qb + (mt * 16 + arow) * 32 + kc);
  bf16x8 qa = __builtin_bit_cast(bf16x8, qraw);
  f32x4 s[4];
#pragma unroll
  for (int ni = 0; ni < 4; ni++) {
    uint4 kraw = *reinterpret_cast<const uint4*>(kb + (ni * 16 + arow) * 32 + kc);
    f32x4 z = {0.f, 0.f, 0.f, 0.f};
    s[ni] = __builtin_amdgcn_mfma_f32_16x16x32_bf16(
        qa, __builtin_bit_cast(bf16x8, kraw), z, 0, 0, 0);
  }

  const int rg = (lane >> 4) * 4;
  float rsum[4];
#pragma unroll
  for (int r = 0; r < 4; r++) {
    const int qr = mt * 16 + rg + r;
    float sv[4];
    float mx = -1e30f;
#pragma unroll
    for (int ni = 0; ni < 4; ni++) {
      const int col = ni * 16 + arow;
      float v;
      if (qr < 49 && col < 49)
        v = s[ni][r] * SCALE_F + mask[(size_t)w * 2401 + qr * 49 + col];
      else
        v = -1e30f;
      sv[ni] = v;
      mx = fmaxf(mx, v);
    }
#pragma unroll
    for (int off = 1; off < 16; off <<= 1) mx = fmaxf(mx, __shfl_xor(mx, off));
    float sum = 0.f;
    const int prow = rg + r;
#pragma unroll
    for (int ni = 0; ni < 4; ni++) {
      float p = __expf(sv[ni] - mx);
      sum += p;
      const int pcol = ni * 16 + arow;
      Ps[mt][prow][(((pcol >> 3) ^ (prow & 7)) << 3) | (pcol & 7)] = f2bf(p);
    }
#pragma unroll
    for (int off = 1; off < 16; off <<= 1) sum += __shfl_xor(sum, off);
    rsum[r] = sum;
  }

  __syncthreads();

  f32x4 o0 = {0.f, 0.f, 0.f, 0.f}, o1 = {0.f, 0.f, 0.f, 0.f};
#pragma unroll
  for (int kk = 0; kk < 2; kk++) {
    const int ch = kk * 4 + (lane >> 4);
    const int cb = ((ch ^ (lane & 7)) << 3);
    uint4 praw = *reinterpret_cast<const uint4*>(&Ps[mt][arow][cb]);
    bf16x8 pa = __builtin_bit_cast(bf16x8, praw);
    uint4 v0 = *reinterpret_cast<const uint4*>(&Vt[arow][cb]);
    uint4 v1 = *reinterpret_cast<const uint4*>(&Vt[16 + arow][cb]);
    o0 = __builtin_amdgcn_mfma_f32_16x16x32_bf16(pa, __builtin_bit_cast(bf16x8, v0), o0, 0, 0, 0);
    o1 = __builtin_amdgcn_mfma_f32_16x16x32_bf16(pa, __builtin_bit_cast(bf16x8, v1), o1, 0, 0, 0);
  }

#pragma unroll
  for (int r = 0; r < 4; r++) {
    const int qr = mt * 16 + rg + r;
    if (qr < 49) {
      const float inv = 1.f / rsum[r];
      aout[((size_t)b * 49 + qr) * 512 + h * 32 + arow]      = f2bf(o0[r] * inv);
      aout[((size_t)b * 49 + qr) * 512 + h * 32 + 16 + arow] = f2bf(o1[r] * inv);
    }
  }
}

// ---------------------------------------------------------------------------
// launch
// ---------------------------------------------------------------------------
extern "C" void kernel_launch(void* const* d_in, const int* in_sizes, int n_in,
                              void* d_out, int out_size, void* d_ws, size_t ws_size,
                              hipStream_t stream) {
  const float* x      = (const float*)d_in[0];
  const float* mask   = (const float*)d_in[1];
  const float* W_qkv  = (const float*)d_in[2];
  const float* b_qkv  = (const float*)d_in[3];
  const float* W_proj = (const float*)d_in[4];
  const float* b_proj = (const float*)d_in[5];
  float* out = (float*)d_out;

  // ws layout (bf16 elems): xb | qkv(q,k,v) | attn_out | Wqkv_b | Wproj_b
  ushort_t* ws     = (ushort_t*)d_ws;
  ushort_t* xb     = ws;                                  // 51,380,224
  ushort_t* qkvb   = ws + 51380224UL;                     // 3*51,380,224
  ushort_t* aoutb  = ws + 205520896UL;                    // 51,380,224
  ushort_t* wqkvb  = ws + 256901120UL;                    // 786,432
  ushort_t* wprojb = ws + 257687552UL;                    // 262,144

  const int n4x = 51380224 / 4, n4q = 786432 / 4, n4p = 262144 / 4;
  k_cvt<<<(n4x + 255) / 256, 256, 0, stream>>>(x, xb, n4x);
  k_cvt<<<(n4q + 255) / 256, 256, 0, stream>>>(W_qkv, wqkvb, n4q);
  k_cvt<<<(n4p + 255) / 256, 256, 0, stream>>>(W_proj, wprojb, n4p);

  // GEMM1: [100352,512] x [1536,512]^T -> qkv scatter. 784 x 12 tiles.
  k_gemmP<0><<<784 * 12, 256, 0, stream>>>(xb, wqkvb, b_qkv, qkvb, nullptr, 12);

  // attention: one block per (b,h)
  k_attn<<<2048 * 16, 256, 0, stream>>>(qkvb, mask, aoutb);

  // GEMM2: [100352,512] x [512,512]^T + bias -> fp32 out.
  k_gemmP<1><<<784 * 4, 256, 0, stream>>>(aoutb, wprojb, b_proj, nullptr, out, 4);
}

// Round 7
// 574.747 us; speedup vs baseline: 1.2414x; 1.0469x over previous
//
#include <hip/hip_runtime.h>

// ---------------------------------------------------------------------------
// WindowAttention: x[2048,49,512] fp32 -> out[2048,49,512] fp32
// R1: T2 LDS XOR-swizzle + T1 XCD swizzle (bank conflicts -> 0).   [593us]
// R2: 8-phase 256^2 port REGRESSED (K=512 too shallow) - reverted.
// R3: fused x-cvt + raw s_barrier guard -> RACE (raw barrier is no fence).
// R4: fused x-cvt + syncthreads -> 480us (reg-staged A loses). Reverted.
// R5: 2-deep counted-vmcnt pipeline -> 287us NEUTRAL vs R1 270. Conclusion:
//     GEMM at this shape is structure-plateaued; schedule tweaks don't pay.
// R6: GEMMs reverted to R1-proven bits. Attention rewritten wave-per-head
//     (4 heads/block, grid 8192): 16 S-MFMAs/wave, 2-half S to cap VGPR.
// ---------------------------------------------------------------------------

typedef unsigned short ushort_t;
typedef __bf16 bf16x8 __attribute__((ext_vector_type(8)));
typedef float f32x4 __attribute__((ext_vector_type(4)));
typedef unsigned short us8 __attribute__((ext_vector_type(8)));

#define SCALE_F 0.17677669529663687f   // 32^-0.5
constexpr size_t QKV_REG = 2048ULL * 16 * 49 * 32;   // elems per q/k/v region

// RNE float -> bf16 (as raw ushort)
__device__ __forceinline__ ushort_t f2bf(float f) {
  unsigned u = __builtin_bit_cast(unsigned, f);
  u += 0x7FFFu + ((u >> 16) & 1u);
  return (ushort_t)(u >> 16);
}

// async global->LDS, 16B per lane; lds base must be wave-uniform
__device__ __forceinline__ void gload_lds16(const void* g, void* l) {
  __builtin_amdgcn_global_load_lds(
      (const __attribute__((address_space(1))) void*)g,
      (__attribute__((address_space(3))) void*)l, 16, 0, 0);
}

// ---------------------------------------------------------------------------
// fp32 -> bf16 conversion, 4 elems/thread
// ---------------------------------------------------------------------------
__global__ __launch_bounds__(256) void k_cvt(const float* __restrict__ in,
                                             ushort_t* __restrict__ out, int n4) {
  int i = blockIdx.x * blockDim.x + threadIdx.x;
  if (i >= n4) return;
  float4 v = reinterpret_cast<const float4*>(in)[i];
  ushort4 o = make_ushort4(f2bf(v.x), f2bf(v.y), f2bf(v.z), f2bf(v.w));
  reinterpret_cast<ushort4*>(out)[i] = o;
}

// ---------------------------------------------------------------------------
// GEMM (R1-proven): C[m][o] = sum_k A[m][k] * W[o][k] + bias[o]
// 128x128 tile, BK=64, 4 waves, gload_lds staging, XOR-swizzled LDS
// (slot(row,c) holds logical chunk c^(row&7); pre-swizzled global source).
// EPI=0: scatter to qkv layout [3][B,H,N,d] bf16.  EPI=1: fp32 out.
// ---------------------------------------------------------------------------
template <int EPI>
__global__ __launch_bounds__(256) void k_gemm(const ushort_t* __restrict__ A,
                                              const ushort_t* __restrict__ W,
                                              const float* __restrict__ bias,
                                              ushort_t* __restrict__ out_qkv,
                                              float* __restrict__ out_f,
                                              int nt_o) {
  __shared__ __align__(16) ushort_t As[128][64];
  __shared__ __align__(16) ushort_t Ws[128][64];

  const int tid  = threadIdx.x;
  const int lane = tid & 63;
  const int wv   = tid >> 6;
  const int wr   = wv >> 1, wc = wv & 1;

  const int cpx = gridDim.x >> 3;
  const int lid = (blockIdx.x & 7) * cpx + (blockIdx.x >> 3);
  const int bm  = lid / nt_o;
  const int bo  = lid - bm * nt_o;
  const size_t m0 = (size_t)bm * 128;
  const int o0    = bo * 128;

  f32x4 acc[4][4];
#pragma unroll
  for (int i = 0; i < 4; i++)
#pragma unroll
    for (int j = 0; j < 4; j++) acc[i][j] = f32x4{0.f, 0.f, 0.f, 0.f};

  const int srow   = wv * 32 + (lane >> 3);
  const int schunk = (((lane & 7) ^ (lane >> 3)) * 8);

  for (int kt = 0; kt < 8; ++kt) {
    const int k0 = kt * 64;
#pragma unroll
    for (int i = 0; i < 4; i++)
      gload_lds16(A + (m0 + srow + i * 8) * 512 + k0 + schunk,
                  &As[wv * 32 + i * 8][0]);
#pragma unroll
    for (int i = 0; i < 4; i++)
      gload_lds16(W + (size_t)(o0 + srow + i * 8) * 512 + k0 + schunk,
                  &Ws[wv * 32 + i * 8][0]);
    __syncthreads();
    const int fr = lane & 15;
#pragma unroll
    for (int kk = 0; kk < 2; ++kk) {
      const int ch = kk * 4 + (lane >> 4);
      const int cb = ((ch ^ (lane & 7)) << 3);
      uint4 ar[4], br[4];
#pragma unroll
      for (int mi = 0; mi < 4; mi++)
        ar[mi] = *reinterpret_cast<const uint4*>(&As[wr * 64 + mi * 16 + fr][cb]);
#pragma unroll
      for (int ni = 0; ni < 4; ni++)
        br[ni] = *reinterpret_cast<const uint4*>(&Ws[wc * 64 + ni * 16 + fr][cb]);
#pragma unroll
      for (int mi = 0; mi < 4; mi++)
#pragma unroll
        for (int ni = 0; ni < 4; ni++)
          acc[mi][ni] = __builtin_amdgcn_mfma_f32_16x16x32_bf16(
              __builtin_bit_cast(bf16x8, ar[mi]),
              __builtin_bit_cast(bf16x8, br[ni]), acc[mi][ni], 0, 0, 0);
    }
    __syncthreads();
  }

  const int colbase = lane & 15;
  const int rowgrp  = (lane >> 4) * 4;

  if constexpr (EPI == 1) {
#pragma unroll
    for (int ni = 0; ni < 4; ni++) {
      const int o = o0 + wc * 64 + ni * 16 + colbase;
      const float bv = bias[o];
#pragma unroll
      for (int mi = 0; mi < 4; mi++) {
        const size_t mrow = m0 + wr * 64 + mi * 16 + rowgrp;
#pragma unroll
        for (int r = 0; r < 4; r++)
          out_f[(mrow + r) * 512 + o] = acc[mi][ni][r] + bv;
      }
    }
  } else {
#pragma unroll
    for (int mi = 0; mi < 4; mi++) {
#pragma unroll
      for (int r = 0; r < 4; r++) {
        const int t = (int)m0 + wr * 64 + mi * 16 + rowgrp + r;  // token
        const int b = t / 49;
        const int n = t - b * 49;
#pragma unroll
        for (int ni = 0; ni < 4; ni++) {
          const int o = o0 + wc * 64 + ni * 16 + colbase;
          const int which = o >> 9;
          const int h = (o >> 5) & 15;
          const int dd = o & 31;
          const size_t dst = (size_t)which * QKV_REG +
                             (((size_t)b * 16 + h) * 49 + n) * 32 + dd;
          out_qkv[dst] = f2bf(acc[mi][ni][r] + bias[o]);
        }
      }
    }
  }
}

// ---------------------------------------------------------------------------
// Attention v2: wave-per-head. Block = 4 heads of one window-batch b;
// grid = 2048*4. Each wave: full 64x64 (49 valid) S = Q K^T (16 MFMAs, in two
// 32-row halves to cap VGPR), softmax with mask, P -> Ps[wv] (swizzled),
// V -> Vt[wv] transposed (swizzled), O = P V / rowsum.
// All XOR-swizzle invariants identical to the R1-verified kernel (row bases
// are multiples of 16, so row&7 == lane&7 / prow&7 / j as before).
// ---------------------------------------------------------------------------
__global__ __launch_bounds__(256) void k_attn4(const ushort_t* __restrict__ qkv,
                                               const float* __restrict__ mask,
                                               ushort_t* __restrict__ aout) {
  __shared__ __align__(16) ushort_t Vt[4][32][64];   // per-wave V^T (swizzled)
  __shared__ __align__(16) ushort_t Ps[4][64][64];   // per-wave P (swizzled)

  const int tid  = threadIdx.x;
  const int lane = tid & 63;
  const int wv   = tid >> 6;
  const int blk  = blockIdx.x;
  const int b    = blk >> 2;
  const int h    = (blk & 3) * 4 + wv;
  const int w    = b & 63;
  const size_t base = (((size_t)b * 16 + h)) * (49 * 32);
  const ushort_t* qb = qkv + base;
  const ushort_t* kb = qkv + QKV_REG + base;
  const ushort_t* vb = qkv + 2 * QKV_REG + base;

  // zero own Vt region (pad cols), then barrier, then transposed V write
  {
    uint4* vz = reinterpret_cast<uint4*>(&Vt[wv][0][0]);
#pragma unroll
    for (int i = 0; i < 4; i++) vz[i * 64 + lane] = make_uint4(0, 0, 0, 0);
  }
  __syncthreads();
#pragma unroll
  for (int i = 0; i < 4; i++) {
    const int e = lane + (i << 6);
    if (e < 196) {
      const int n = e >> 2, d0 = (e & 3) * 8;
      uint4 raw = *reinterpret_cast<const uint4*>(vb + n * 32 + d0);
      us8 ev = __builtin_bit_cast(us8, raw);
#pragma unroll
      for (int j = 0; j < 8; j++)
        Vt[wv][d0 + j][(((n >> 3) ^ j) << 3) | (n & 7)] = ev[j];
    }
  }

  const int arow = lane & 15;
  const int kc   = (lane >> 4) * 8;
  const int rg   = (lane >> 4) * 4;

  // K fragments (live across both halves)
  uint4 kf[4];
#pragma unroll
  for (int ni = 0; ni < 4; ni++)
    kf[ni] = *reinterpret_cast<const uint4*>(kb + (ni * 16 + arow) * 32 + kc);

  float rsum[4][4];

  // S + softmax in two halves (mt = 2*hm + j) to limit live registers
#pragma unroll
  for (int hm = 0; hm < 2; hm++) {
    f32x4 s2[2][4];
#pragma unroll
    for (int j = 0; j < 2; j++) {
      const int mt = hm * 2 + j;
      uint4 qraw = *reinterpret_cast<const uint4*>(qb + (mt * 16 + arow) * 32 + kc);
      bf16x8 qa = __builtin_bit_cast(bf16x8, qraw);
#pragma unroll
      for (int ni = 0; ni < 4; ni++) {
        f32x4 z = {0.f, 0.f, 0.f, 0.f};
        s2[j][ni] = __builtin_amdgcn_mfma_f32_16x16x32_bf16(
            qa, __builtin_bit_cast(bf16x8, kf[ni]), z, 0, 0, 0);
      }
    }
#pragma unroll
    for (int j = 0; j < 2; j++) {
      const int mt = hm * 2 + j;
#pragma unroll
      for (int r = 0; r < 4; r++) {
        const int qr = mt * 16 + rg + r;
        float sv[4];
        float mx = -1e30f;
#pragma unroll
        for (int ni = 0; ni < 4; ni++) {
          const int col = ni * 16 + arow;
          float v;
          if (qr < 49 && col < 49)
            v = s2[j][ni][r] * SCALE_F + mask[(size_t)w * 2401 + qr * 49 + col];
          else
            v = -1e30f;
          sv[ni] = v;
          mx = fmaxf(mx, v);
        }
#pragma unroll
        for (int off = 1; off < 16; off <<= 1) mx = fmaxf(mx, __shfl_xor(mx, off));
        float sum = 0.f;
        const int prow = rg + r;              // 0..15 within mt tile
#pragma unroll
        for (int ni = 0; ni < 4; ni++) {
          float p = __expf(sv[ni] - mx);
          sum += p;
          const int pcol = ni * 16 + arow;
          Ps[wv][mt * 16 + prow]
            [(((pcol >> 3) ^ (prow & 7)) << 3) | (pcol & 7)] = f2bf(p);
        }
#pragma unroll
        for (int off = 1; off < 16; off <<= 1) sum += __shfl_xor(sum, off);
        rsum[mt][r] = sum;
      }
    }
  }

  __syncthreads();   // fence Vt + Ps writes before uint4 reads

  // V fragments (shared across mt)
  uint4 vf0[2], vf1[2];
#pragma unroll
  for (int kk = 0; kk < 2; kk++) {
    const int ch = kk * 4 + (lane >> 4);
    const int cb = ((ch ^ (lane & 7)) << 3);
    vf0[kk] = *reinterpret_cast<const uint4*>(&Vt[wv][arow][cb]);
    vf1[kk] = *reinterpret_cast<const uint4*>(&Vt[wv][16 + arow][cb]);
  }

  // O = P V per mt tile
#pragma unroll
  for (int mt = 0; mt < 4; mt++) {
    f32x4 o0 = {0.f, 0.f, 0.f, 0.f}, o1 = {0.f, 0.f, 0.f, 0.f};
#pragma unroll
    for (int kk = 0; kk < 2; kk++) {
      const int ch = kk * 4 + (lane >> 4);
      const int cb = ((ch ^ (lane & 7)) << 3);
      uint4 praw = *reinterpret_cast<const uint4*>(&Ps[wv][mt * 16 + arow][cb]);
      bf16x8 pa = __builtin_bit_cast(bf16x8, praw);
      o0 = __builtin_amdgcn_mfma_f32_16x16x32_bf16(
          pa, __builtin_bit_cast(bf16x8, vf0[kk]), o0, 0, 0, 0);
      o1 = __builtin_amdgcn_mfma_f32_16x16x32_bf16(
          pa, __builtin_bit_cast(bf16x8, vf1[kk]), o1, 0, 0, 0);
    }
#pragma unroll
    for (int r = 0; r < 4; r++) {
      const int qr = mt * 16 + rg + r;
      if (qr < 49) {
        const float inv = 1.f / rsum[mt][r];
        aout[((size_t)b * 49 + qr) * 512 + h * 32 + arow]      = f2bf(o0[r] * inv);
        aout[((size_t)b * 49 + qr) * 512 + h * 32 + 16 + arow] = f2bf(o1[r] * inv);
      }
    }
  }
}

// ---------------------------------------------------------------------------
// launch
// ---------------------------------------------------------------------------
extern "C" void kernel_launch(void* const* d_in, const int* in_sizes, int n_in,
                              void* d_out, int out_size, void* d_ws, size_t ws_size,
                              hipStream_t stream) {
  const float* x      = (const float*)d_in[0];
  const float* mask   = (const float*)d_in[1];
  const float* W_qkv  = (const float*)d_in[2];
  const float* b_qkv  = (const float*)d_in[3];
  const float* W_proj = (const float*)d_in[4];
  const float* b_proj = (const float*)d_in[5];
  float* out = (float*)d_out;

  // ws layout (bf16 elems): xb | qkv(q,k,v) | attn_out | Wqkv_b | Wproj_b
  ushort_t* ws     = (ushort_t*)d_ws;
  ushort_t* xb     = ws;                                  // 51,380,224
  ushort_t* qkvb   = ws + 51380224UL;                     // 3*51,380,224
  ushort_t* aoutb  = ws + 205520896UL;                    // 51,380,224
  ushort_t* wqkvb  = ws + 256901120UL;                    // 786,432
  ushort_t* wprojb = ws + 257687552UL;                    // 262,144

  const int n4x = 51380224 / 4, n4q = 786432 / 4, n4p = 262144 / 4;
  k_cvt<<<(n4x + 255) / 256, 256, 0, stream>>>(x, xb, n4x);
  k_cvt<<<(n4q + 255) / 256, 256, 0, stream>>>(W_qkv, wqkvb, n4q);
  k_cvt<<<(n4p + 255) / 256, 256, 0, stream>>>(W_proj, wprojb, n4p);

  // GEMM1: [100352,512] x [1536,512]^T -> qkv scatter. 784 x 12 tiles.
  k_gemm<0><<<784 * 12, 256, 0, stream>>>(xb, wqkvb, b_qkv, qkvb, nullptr, 12);

  // attention: block = 4 heads, wave = 1 head
  k_attn4<<<2048 * 4, 256, 0, stream>>>(qkvb, mask, aoutb);

  // GEMM2: [100352,512] x [512,512]^T + bias -> fp32 out.
  k_gemm<1><<<784 * 4, 256, 0, stream>>>(aoutb, wprojb, b_proj, nullptr, out, 4);
}